// Round 14
// baseline (99.384 us; speedup 1.0000x reference)
//
#include <hip/hip_runtime.h>
#include <stdint.h>

// ClusterHead: P = softmax_k( x . c_k - 0.5*||c_k||^2 )   (||x||^2 cancels)
// R14: 4 waves/SIMD by construction. 1024-thread block (16 waves), tile
// 64 rows x 1024 cols, wave = 64x64 -> acc[2][2] f32x16 = 64 AGPR; slim
// operand set (a 16 + b 16 + ~45 misc) fits the 128-reg cap that 4
// waves/SIMD requires (launch_bounds(1024,4) pins it). MFMA reality: one
// 32x32x16 occupies ~32 SIMD-cycles (2178 TF is the per-CU rate) -- R11/R13
// at 2 waves/SIMD were issue-starved (15.5% = exact arithmetic match).
// Single-term fp16 GEMM (absmax 0.0078 validated), A-panel staged once to
// LDS (XOR swizzle), barrier-free K-loop, B direct L2->reg 4-frag loads,
// NT x-loads / out-stores. B-traffic stays 0.5GB (64-row blocks).
// B-pack: 32 images of 32KB; image (T*2+ks): [cb(32)][(c32*2+kh)*8]
// halfwords. MFMA B operand: col=l&31, k=(l>>5)*8+e per 16-k group.

namespace {
constexpr int N_ROWS  = 32768;
constexpr int K_CL    = 1024;
constexpr int D_DIM   = 512;
constexpr int BM      = 64;
constexpr int THREADS = 1024;
constexpr int WAVES   = 16;
constexpr int NSLICE  = 16;
}

typedef _Float16 f16_t;
typedef _Float16 f16x8 __attribute__((ext_vector_type(8)));
typedef _Float16 f16x4 __attribute__((ext_vector_type(4)));
typedef float    f32x16 __attribute__((ext_vector_type(16)));
typedef float    f32x4v __attribute__((ext_vector_type(4)));

// ---- prep: fp16 B-pack + bias = -0.5*||c||^2 (fp32 exact) ----
__global__ __launch_bounds__(64) void prep_kernel(const float* __restrict__ centers,
                                                  f16_t* __restrict__ bpack,
                                                  float* __restrict__ bias) {
  const int col = blockIdx.x, lane = threadIdx.x;
  const int t  = lane >> 2;          // k-slice (d>>5)
  const int ks = (lane >> 1) & 1;    // 16-k group
  const int kh = lane & 1;           // 8-k half
  const float* src = centers + (size_t)col * D_DIM + lane * 8;
  f16x8 hi;
  float ssq = 0.f;
  #pragma unroll
  for (int i = 0; i < 8; ++i) {
    float v = src[i];
    ssq += v * v;
    hi[i] = (f16_t)v;
  }
  const int cb = col >> 5, c32 = col & 31;
  *(f16x8*)(bpack + (size_t)(t * 2 + ks) * 16384 + cb * 512 + (c32 * 2 + kh) * 8) = hi;
  for (int o = 32; o; o >>= 1) ssq += __shfl_down(ssq, o, 64);
  if (lane == 0) bias[col] = -0.5f * ssq;
}

// ---- main fused kernel: 64 rows x 1024 cols, 16 waves, 4 waves/SIMD ----
__global__ __launch_bounds__(THREADS, 4) void cluster_kernel(
    const float* __restrict__ x, const f16_t* __restrict__ bpack,
    const float* __restrict__ bias, float* __restrict__ out) {
  __shared__ __align__(16) char Ax[65536];   // 64KB swizzled A panel
  __shared__ float red[WAVES * BM];          // 4KB
  __shared__ float fin[BM];

  const int tid  = threadIdx.x;
  const int w    = tid >> 6;       // wave 0..15 -> cols [w*64, +64)
  const int lane = tid & 63;
  const int l31  = lane & 31;
  const int h    = lane >> 5;
  const int brow = blockIdx.x * BM;

  // per-lane byte base into an image: wave's 2 cb-blocks at w*2048
  const char* bbase = (const char*)bpack + w * 2048 + (l31 * 2 + h) * 16;

  // ---- stage A panel -> LDS fp16 (coalesced NT reads, swizzled writes) ----
  {
    const float* xsrc = x + (size_t)brow * D_DIM;
    #pragma unroll
    for (int it = 0; it < 8; ++it) {
      const int idx = it * 1024 + tid;         // float4 index (64*128 total)
      const int r = idx >> 7, f = idx & 127;
      f32x4v v = __builtin_nontemporal_load(
          (const f32x4v*)(xsrc + (size_t)r * D_DIM + f * 4));
      f16x4 h4;
      h4[0] = (f16_t)v[0]; h4[1] = (f16_t)v[1];
      h4[2] = (f16_t)v[2]; h4[3] = (f16_t)v[3];
      *(f16x4*)(Ax + r * 1024 + ((f * 8) ^ ((r & 7) << 4))) = h4;
    }
  }
  __syncthreads();   // the only pre-epilogue barrier

  f32x16 acc[2][2];
  #pragma unroll
  for (int rb = 0; rb < 2; ++rb)
    #pragma unroll
    for (int cc = 0; cc < 2; ++cc)
      #pragma unroll
      for (int e = 0; e < 16; ++e) acc[rb][cc][e] = 0.f;

  const char* abase = Ax + l31 * 1024;
  const int swz = (l31 & 7) << 4;

  // ---- K loop: 16 slices, barrier-free ----
  #pragma unroll
  for (int T = 0; T < NSLICE; ++T) {
    const char* p0 = bbase + (size_t)T * 65536;          // image (T,ks=0)
    f16x8 b00 = *(const f16x8*)(p0);
    f16x8 b01 = *(const f16x8*)(p0 + 1024);
    f16x8 b10 = *(const f16x8*)(p0 + 32768);             // image (T,ks=1)
    f16x8 b11 = *(const f16x8*)(p0 + 32768 + 1024);
    const int o0 = (T * 64 + h * 16) ^ swz;              // ks0 bytes
    const f16x8 a00 = *(const f16x8*)(abase + o0);
    const f16x8 a01 = *(const f16x8*)(abase + (o0 ^ 32));          // ks1
    const f16x8 a10 = *(const f16x8*)(abase + 32768 + o0);
    const f16x8 a11 = *(const f16x8*)(abase + 32768 + (o0 ^ 32));
    acc[0][0] = __builtin_amdgcn_mfma_f32_32x32x16_f16(a00, b00, acc[0][0], 0, 0, 0);
    acc[0][1] = __builtin_amdgcn_mfma_f32_32x32x16_f16(a00, b01, acc[0][1], 0, 0, 0);
    acc[1][0] = __builtin_amdgcn_mfma_f32_32x32x16_f16(a10, b00, acc[1][0], 0, 0, 0);
    acc[1][1] = __builtin_amdgcn_mfma_f32_32x32x16_f16(a10, b01, acc[1][1], 0, 0, 0);
    acc[0][0] = __builtin_amdgcn_mfma_f32_32x32x16_f16(a01, b10, acc[0][0], 0, 0, 0);
    acc[0][1] = __builtin_amdgcn_mfma_f32_32x32x16_f16(a01, b11, acc[0][1], 0, 0, 0);
    acc[1][0] = __builtin_amdgcn_mfma_f32_32x32x16_f16(a11, b10, acc[1][0], 0, 0, 0);
    acc[1][1] = __builtin_amdgcn_mfma_f32_32x32x16_f16(a11, b11, acc[1][1], 0, 0, 0);
  }

  // ---- epilogue: fused softmax over 1024 columns ----
  // col(cc) = w*64 + cc*32 + l31 ; row(rb,reg) = rb*32 + (reg&3)+8*(reg>>2)+4*h
  float bcol[2];
  #pragma unroll
  for (int cc = 0; cc < 2; ++cc)
    bcol[cc] = bias[w * 64 + cc * 32 + l31];

  #pragma unroll
  for (int rb = 0; rb < 2; ++rb)
    #pragma unroll
    for (int reg = 0; reg < 16; ++reg) {
      float v0 = acc[rb][0][reg] + bcol[0];
      float v1 = acc[rb][1][reg] + bcol[1];
      acc[rb][0][reg] = v0;
      acc[rb][1][reg] = v1;
      float m = fmaxf(v0, v1);
      m = fmaxf(m, __shfl_xor(m, 1, 64));
      m = fmaxf(m, __shfl_xor(m, 2, 64));
      m = fmaxf(m, __shfl_xor(m, 4, 64));
      m = fmaxf(m, __shfl_xor(m, 8, 64));
      m = fmaxf(m, __shfl_xor(m, 16, 64));
      if (l31 == 0)
        red[w * BM + rb * 32 + (reg & 3) + 8 * (reg >> 2) + 4 * h] = m;
    }
  __syncthreads();
  if (tid < BM) {
    float m = red[tid];
    #pragma unroll
    for (int ww = 1; ww < WAVES; ++ww) m = fmaxf(m, red[ww * BM + tid]);
    fin[tid] = m;
  }
  __syncthreads();

  #pragma unroll
  for (int rb = 0; rb < 2; ++rb)
    #pragma unroll
    for (int reg = 0; reg < 16; ++reg) {
      const float m = fin[rb * 32 + (reg & 3) + 8 * (reg >> 2) + 4 * h];
      float e0 = __expf(acc[rb][0][reg] - m);
      float e1 = __expf(acc[rb][1][reg] - m);
      acc[rb][0][reg] = e0;
      acc[rb][1][reg] = e1;
      float s = e0 + e1;
      s += __shfl_xor(s, 1, 64);
      s += __shfl_xor(s, 2, 64);
      s += __shfl_xor(s, 4, 64);
      s += __shfl_xor(s, 8, 64);
      s += __shfl_xor(s, 16, 64);
      if (l31 == 1)    // distinct lane from max-writer; same row coverage
        red[w * BM + rb * 32 + (reg & 3) + 8 * (reg >> 2) + 4 * h] = s;
    }
  __syncthreads();
  if (tid < BM) {
    float s = 0.f;
    #pragma unroll
    for (int ww = 0; ww < WAVES; ++ww) s += red[ww * BM + tid];
    fin[tid] = 1.0f / s;
  }
  __syncthreads();

  #pragma unroll
  for (int rb = 0; rb < 2; ++rb)
    #pragma unroll
    for (int reg = 0; reg < 16; ++reg) {
      const int row = rb * 32 + (reg & 3) + 8 * (reg >> 2) + 4 * h;
      const float rs = fin[row];
      #pragma unroll
      for (int cc = 0; cc < 2; ++cc)
        __builtin_nontemporal_store(acc[rb][cc][reg] * rs,
            &out[(size_t)(brow + row) * K_CL + w * 64 + cc * 32 + l31]);
    }
}

extern "C" void kernel_launch(void* const* d_in, const int* in_sizes, int n_in,
                              void* d_out, int out_size, void* d_ws, size_t ws_size,
                              hipStream_t stream) {
  const float* x       = (const float*)d_in[0];   // [32768, 512] fp32
  const float* centers = (const float*)d_in[1];   // [1024, 512] fp32
  float* out = (float*)d_out;                     // [32768, 1024] fp32

  f16_t* bpack = (f16_t*)d_ws;                                   // 32*32KB = 1MB
  float* bias  = (float*)((char*)d_ws + (size_t)32 * 32768);     // 4KB

  prep_kernel<<<K_CL, 64, 0, stream>>>(centers, bpack, bias);
  cluster_kernel<<<N_ROWS / BM, THREADS, 0, stream>>>(x, bpack, bias, out);
}

// Round 15
// 98.949 us; speedup vs baseline: 1.0044x; 1.0044x over previous
//
#include <hip/hip_runtime.h>
#include <stdint.h>

// ClusterHead: P = softmax_k( x . c_k - 0.5*||c_k||^2 )   (||x||^2 cancels)
// R15 = R14 + (a) depth-3 half-slice rolling B prefetch (2-half-slice gap
// ~296cy covers L2 latency) within the 128-reg cap that 1024-thread blocks
// REQUIRE (16 waves -> 4/SIMD -> <=128 unified regs; 512-reg pool/SIMD);
// (b) 5-bit row XOR swizzle (exact 32-bank spread, kills R14's 2.1M
// conflicts). Single-term fp16 GEMM (absmax 0.0078), 32x32x16 f16 MFMA,
// A-panel staged once to LDS, barrier-free K-loop, NT x-loads/out-stores,
// grid 512 = 2 rounds (round-boundary store-drain overlap).
// B-pack: 32 images of 32KB, image j = half-slice j (T=j>>1, ks=j&1):
// [cb(32)][(c32*2+kh)*8] halfwords -> byte offset j*32768 (linear in j).

namespace {
constexpr int N_ROWS  = 32768;
constexpr int K_CL    = 1024;
constexpr int D_DIM   = 512;
constexpr int BM      = 64;
constexpr int THREADS = 1024;
constexpr int WAVES   = 16;
}

typedef _Float16 f16_t;
typedef _Float16 f16x8 __attribute__((ext_vector_type(8)));
typedef _Float16 f16x4 __attribute__((ext_vector_type(4)));
typedef float    f32x16 __attribute__((ext_vector_type(16)));
typedef float    f32x4v __attribute__((ext_vector_type(4)));

// ---- prep: fp16 B-pack + bias = -0.5*||c||^2 (fp32 exact) ----
__global__ __launch_bounds__(64) void prep_kernel(const float* __restrict__ centers,
                                                  f16_t* __restrict__ bpack,
                                                  float* __restrict__ bias) {
  const int col = blockIdx.x, lane = threadIdx.x;
  const int t  = lane >> 2;          // k-slice (d>>5)
  const int ks = (lane >> 1) & 1;    // 16-k group
  const int kh = lane & 1;           // 8-k half
  const float* src = centers + (size_t)col * D_DIM + lane * 8;
  f16x8 hi;
  float ssq = 0.f;
  #pragma unroll
  for (int i = 0; i < 8; ++i) {
    float v = src[i];
    ssq += v * v;
    hi[i] = (f16_t)v;
  }
  const int cb = col >> 5, c32 = col & 31;
  *(f16x8*)(bpack + (size_t)(t * 2 + ks) * 16384 + cb * 512 + (c32 * 2 + kh) * 8) = hi;
  for (int o = 32; o; o >>= 1) ssq += __shfl_down(ssq, o, 64);
  if (lane == 0) bias[col] = -0.5f * ssq;
}

// ---- main fused kernel: 64 rows x 1024 cols, 16 waves, 4 waves/SIMD ----
__global__ __launch_bounds__(THREADS, 4) void cluster_kernel(
    const float* __restrict__ x, const f16_t* __restrict__ bpack,
    const float* __restrict__ bias, float* __restrict__ out) {
  __shared__ __align__(16) char Ax[65536];   // 64KB swizzled A panel
  __shared__ float red[WAVES * BM];          // 4KB
  __shared__ float fin[BM];

  const int tid  = threadIdx.x;
  const int w    = tid >> 6;       // wave 0..15 -> cols [w*64, +64)
  const int lane = tid & 63;
  const int l31  = lane & 31;
  const int h    = lane >> 5;
  const int brow = blockIdx.x * BM;

  // per-lane byte base into an image: wave's cb-pair at w*2048
  const char* bbase = (const char*)bpack + w * 2048 + (l31 * 2 + h) * 16;

  // ---- stage A panel -> LDS fp16 (coalesced NT reads, swz5 writes) ----
  {
    const float* xsrc = x + (size_t)brow * D_DIM;
    #pragma unroll
    for (int it = 0; it < 8; ++it) {
      const int idx = it * 1024 + tid;         // float4 index (64*128 total)
      const int r = idx >> 7, f = idx & 127;
      f32x4v v = __builtin_nontemporal_load(
          (const f32x4v*)(xsrc + (size_t)r * D_DIM + f * 4));
      f16x4 h4;
      h4[0] = (f16_t)v[0]; h4[1] = (f16_t)v[1];
      h4[2] = (f16_t)v[2]; h4[3] = (f16_t)v[3];
      *(f16x4*)(Ax + r * 1024 + ((f * 8) ^ ((r & 31) << 4))) = h4;
    }
  }
  __syncthreads();   // the only pre-epilogue barrier

  f32x16 acc[2][2];
  #pragma unroll
  for (int rb = 0; rb < 2; ++rb)
    #pragma unroll
    for (int cc = 0; cc < 2; ++cc)
      #pragma unroll
      for (int e = 0; e < 16; ++e) acc[rb][cc][e] = 0.f;

  const char* abase = Ax + l31 * 1024;
  const int swz = l31 << 4;        // 5-bit row XOR (bits 4-8)

  // ---- K loop: 32 half-slices, depth-3 rolling B buffer, barrier-free ----
  f16x8 hb[3][2];                  // [slot][cb frag]; slot = j % 3
#define LOADHB(J)                                                              \
  {                                                                            \
    const char* p_ = bbase + (size_t)(J) * 32768;                              \
    hb[(J) % 3][0] = *(const f16x8*)(p_);                                      \
    hb[(J) % 3][1] = *(const f16x8*)(p_ + 1024);                               \
  }
  LOADHB(0)
  LOADHB(1)
  #pragma unroll
  for (int j = 0; j < 32; ++j) {
    if (j + 2 < 32) { LOADHB(j + 2) }
    // A frags for half-slice j: T = j>>1, ks = j&1 -> byte (T*64+ks*32+h*16)^swz
    const int o = (((j >> 1) * 64 + (j & 1) * 32 + h * 16)) ^ swz;
    const f16x8 a0 = *(const f16x8*)(abase + o);
    const f16x8 a1 = *(const f16x8*)(abase + 32768 + o);
    acc[0][0] = __builtin_amdgcn_mfma_f32_32x32x16_f16(a0, hb[j % 3][0], acc[0][0], 0, 0, 0);
    acc[0][1] = __builtin_amdgcn_mfma_f32_32x32x16_f16(a0, hb[j % 3][1], acc[0][1], 0, 0, 0);
    acc[1][0] = __builtin_amdgcn_mfma_f32_32x32x16_f16(a1, hb[j % 3][0], acc[1][0], 0, 0, 0);
    acc[1][1] = __builtin_amdgcn_mfma_f32_32x32x16_f16(a1, hb[j % 3][1], acc[1][1], 0, 0, 0);
  }

  // ---- epilogue: fused softmax over 1024 columns ----
  // col(cc) = w*64 + cc*32 + l31 ; row(rb,reg) = rb*32 + (reg&3)+8*(reg>>2)+4*h
  float bcol[2];
  #pragma unroll
  for (int cc = 0; cc < 2; ++cc)
    bcol[cc] = bias[w * 64 + cc * 32 + l31];

  #pragma unroll
  for (int rb = 0; rb < 2; ++rb)
    #pragma unroll
    for (int reg = 0; reg < 16; ++reg) {
      float v0 = acc[rb][0][reg] + bcol[0];
      float v1 = acc[rb][1][reg] + bcol[1];
      acc[rb][0][reg] = v0;
      acc[rb][1][reg] = v1;
      float m = fmaxf(v0, v1);
      m = fmaxf(m, __shfl_xor(m, 1, 64));
      m = fmaxf(m, __shfl_xor(m, 2, 64));
      m = fmaxf(m, __shfl_xor(m, 4, 64));
      m = fmaxf(m, __shfl_xor(m, 8, 64));
      m = fmaxf(m, __shfl_xor(m, 16, 64));
      if (l31 == 0)
        red[w * BM + rb * 32 + (reg & 3) + 8 * (reg >> 2) + 4 * h] = m;
    }
  __syncthreads();
  if (tid < BM) {
    float m = red[tid];
    #pragma unroll
    for (int ww = 1; ww < WAVES; ++ww) m = fmaxf(m, red[ww * BM + tid]);
    fin[tid] = m;
  }
  __syncthreads();

  #pragma unroll
  for (int rb = 0; rb < 2; ++rb)
    #pragma unroll
    for (int reg = 0; reg < 16; ++reg) {
      const float m = fin[rb * 32 + (reg & 3) + 8 * (reg >> 2) + 4 * h];
      float e0 = __expf(acc[rb][0][reg] - m);
      float e1 = __expf(acc[rb][1][reg] - m);
      acc[rb][0][reg] = e0;
      acc[rb][1][reg] = e1;
      float s = e0 + e1;
      s += __shfl_xor(s, 1, 64);
      s += __shfl_xor(s, 2, 64);
      s += __shfl_xor(s, 4, 64);
      s += __shfl_xor(s, 8, 64);
      s += __shfl_xor(s, 16, 64);
      if (l31 == 1)    // distinct lane from max-writer; same row coverage
        red[w * BM + rb * 32 + (reg & 3) + 8 * (reg >> 2) + 4 * h] = s;
    }
  __syncthreads();
  if (tid < BM) {
    float s = 0.f;
    #pragma unroll
    for (int ww = 0; ww < WAVES; ++ww) s += red[ww * BM + tid];
    fin[tid] = 1.0f / s;
  }
  __syncthreads();

  #pragma unroll
  for (int rb = 0; rb < 2; ++rb)
    #pragma unroll
    for (int reg = 0; reg < 16; ++reg) {
      const int row = rb * 32 + (reg & 3) + 8 * (reg >> 2) + 4 * h;
      const float rs = fin[row];
      #pragma unroll
      for (int cc = 0; cc < 2; ++cc)
        __builtin_nontemporal_store(acc[rb][cc][reg] * rs,
            &out[(size_t)(brow + row) * K_CL + w * 64 + cc * 32 + l31]);
    }
}

extern "C" void kernel_launch(void* const* d_in, const int* in_sizes, int n_in,
                              void* d_out, int out_size, void* d_ws, size_t ws_size,
                              hipStream_t stream) {
  const float* x       = (const float*)d_in[0];   // [32768, 512] fp32
  const float* centers = (const float*)d_in[1];   // [1024, 512] fp32
  float* out = (float*)d_out;                     // [32768, 1024] fp32

  f16_t* bpack = (f16_t*)d_ws;                                   // 32*32KB = 1MB
  float* bias  = (float*)((char*)d_ws + (size_t)32 * 32768);     // 4KB

  prep_kernel<<<K_CL, 64, 0, stream>>>(centers, bpack, bias);
  cluster_kernel<<<N_ROWS / BM, THREADS, 0, stream>>>(x, bpack, bias, out);
}